// Round 2
// baseline (145.814 us; speedup 1.0000x reference)
//
#include <hip/hip_runtime.h>
#include <stdint.h>

// ---- types ----
typedef __bf16 bf16x8 __attribute__((ext_vector_type(8)));
typedef unsigned short u16x8 __attribute__((ext_vector_type(8)));
typedef float f32x4 __attribute__((ext_vector_type(4)));

// Problem constants
#define CC 64
#define HH 64
#define WW 64
#define OO 128
#define BB 4
#define KSLOT 64   // 9 linear + 45 triu products = 54, padded to 64 (2 MFMA k-steps)

// upper-triangle pair enumeration (i<=j), 45 pairs
__device__ constexpr int PI_[45] = {
  0,0,0,0,0,0,0,0,0,
  1,1,1,1,1,1,1,1,
  2,2,2,2,2,2,2,
  3,3,3,3,3,3,
  4,4,4,4,4,
  5,5,5,5,
  6,6,6,
  7,7,
  8};
__device__ constexpr int PJ_[45] = {
  0,1,2,3,4,5,6,7,8,
  1,2,3,4,5,6,7,8,
  2,3,4,5,6,7,8,
  3,4,5,6,7,8,
  4,5,6,7,8,
  5,6,7,8,
  6,7,8,
  7,8,
  8};

__device__ __forceinline__ unsigned short f2bf(float f) {
  unsigned int u = __float_as_uint(f);
  u = u + 0x7FFFu + ((u >> 16) & 1u);   // RNE
  return (unsigned short)(u >> 16);
}

__device__ __forceinline__ bf16x8 load8(const unsigned short* p) {
  u16x8 v = *(const u16x8*)p;
  return __builtin_bit_cast(bf16x8, v);
}

__device__ __forceinline__ void async_load16(const unsigned short* g, unsigned short* l) {
  __builtin_amdgcn_global_load_lds(
      (const __attribute__((address_space(1))) unsigned int*)g,
      (__attribute__((address_space(3))) unsigned int*)l, 16, 0, 0);
}

// ---- prep: pack wl + triu(wv) into bf16 Wt[c][n][64], chunk-swizzled ----
__global__ void prep_kernel(const float* __restrict__ wl, const float* __restrict__ wv,
                            unsigned short* __restrict__ Wt) {
  int t = blockIdx.x * 256 + threadIdx.x;
  if (t >= CC * OO * KSLOT) return;
  int s = t & 63;
  int n = (t >> 6) & 127;
  int c = t >> 13;
  float v = 0.f;
  if (s < 9) {
    v = wl[(n * CC + c) * 9 + s];
  } else if (s < 54) {
    int p = s - 9, i = 0;
    while (p >= 9 - i) { p -= 9 - i; ++i; }
    int j = i + p;
    v = wv[((n * CC + c) * 9 + i) * 9 + j];
  }
  int jc = s >> 3, e = s & 7;
  int pos = ((jc ^ (n & 7)) << 3) | e;
  Wt[c * (OO * KSLOT) + n * KSLOT + pos] = f2bf(v);
}

// ---- patch-slot filler: wave Q handles slots [Q*16, Q*16+16) ----
template <int Q>
__device__ __forceinline__ void fill_slots(const float p[9], unsigned short* dst) {
  unsigned short h[16];
#pragma unroll
  for (int ss = 0; ss < 16; ++ss) {
    const int s = Q * 16 + ss;
    float v;
    if (s < 9)        v = p[s];
    else if (s < 54)  v = p[PI_[s - 9]] * p[PJ_[s - 9]];
    else              v = 0.f;
    h[ss] = f2bf(v);
  }
  ((uint4*)dst)[0] = *(const uint4*)&h[0];
  ((uint4*)dst)[1] = *(const uint4*)&h[8];
}

// ---- main fused kernel, single barrier per c, fully double-buffered ----
__global__ __launch_bounds__(256) void qconv_kernel(
    const float* __restrict__ img, const unsigned short* __restrict__ Wt,
    const float* __restrict__ bias, float* __restrict__ out) {
  __shared__ unsigned short Pt[2][64][72];        // patch tiles [buf][x][slot], +8 pad
  __shared__ unsigned short Wtile[2][OO * KSLOT]; // weight tiles, chunk-swizzled
  __shared__ float bias_s[OO];

  const int t = threadIdx.x;
  const int lane = t & 63;
  const int wq = t >> 6;       // wave id 0..3 (uniform)
  const int quad = lane >> 4;  // 0..3
  const int u = lane & 15;
  const int wo = wq & 1;       // o-half
  const int wx = wq >> 1;      // x-half
  const int b = blockIdx.x >> 6;
  const int y = blockIdx.x & 63;

  if (t < OO) bias_s[t] = bias[t];

  f32x4 acc[4][2];
#pragma unroll
  for (int mt = 0; mt < 4; ++mt)
#pragma unroll
    for (int nt = 0; nt < 2; ++nt) acc[mt][nt] = (f32x4){0.f, 0.f, 0.f, 0.f};

  // per-lane image row loader: rows y-1, y, y+1 at col = lane for channel c
  auto load_rows = [&](int c, float v[3]) {
#pragma unroll
    for (int r = 0; r < 3; ++r) {
      int yy = y + r - 1;
      v[r] = ((unsigned)yy < 64u) ? img[((b * CC + c) * HH + yy) * WW + lane] : 0.f;
    }
  };

  // build this wave's 16 slots of Pt[pbuf] for the channel whose rows are in v[]
  auto build = [&](const float v[3], unsigned short* dstrow) {
    float p[9];
#pragma unroll
    for (int r = 0; r < 3; ++r) {
      float L = __shfl_up(v[r], 1);
      float R = __shfl_down(v[r], 1);
      p[3 * r + 0] = (lane == 0) ? 0.f : L;
      p[3 * r + 1] = v[r];
      p[3 * r + 2] = (lane == 63) ? 0.f : R;
    }
    switch (wq) {
      case 0: fill_slots<0>(p, dstrow + 0);  break;
      case 1: fill_slots<1>(p, dstrow + 16); break;
      case 2: fill_slots<2>(p, dstrow + 32); break;
      default: fill_slots<3>(p, dstrow + 48); break;
    }
  };

  auto stage_weights = [&](int c, unsigned short* ldst) {
    const unsigned short* gsrc = Wt + c * (OO * KSLOT);
#pragma unroll
    for (int ii = 0; ii < 4; ++ii) {
      int inst = wq * 4 + ii;
      async_load16(gsrc + inst * 512 + lane * 8, ldst + inst * 512);
    }
  };

  // ---- prologue: fill buffer 0 for c=0, prefetch rows of c=1 ----
  float vcur[3];
  load_rows(0, vcur);
  stage_weights(0, &Wtile[0][0]);
  build(vcur, &Pt[0][lane][0]);
  load_rows(1, vcur);            // rows for c=1, consumed next iteration
  __syncthreads();               // drains W[0] async; Pt[0] visible

  for (int c = 0; c < CC; ++c) {
    const int buf = c & 1;
    const int nbuf = buf ^ 1;
    const int cn = (c + 1 < CC) ? c + 1 : CC - 1;

    // prefetch weights for c+1 (safe: all waves past barrier_c, done reading nbuf)
    stage_weights(cn, &Wtile[nbuf][0]);
    // build patch tile for c+1 from prefetched rows
    build(vcur, &Pt[nbuf][lane][0]);
    // prefetch rows for c+2
    load_rows((c + 2 < CC) ? c + 2 : CC - 1, vcur);

    // ---- MFMA on buffer `buf` ----
#pragma unroll
    for (int ks = 0; ks < 2; ++ks) {
      bf16x8 bfrag[2];
#pragma unroll
      for (int nt = 0; nt < 2; ++nt) {
        int x = wx * 32 + nt * 16 + u;
        bfrag[nt] = load8(&Pt[buf][x][ks * 32 + quad * 8]);
      }
#pragma unroll
      for (int mt = 0; mt < 4; ++mt) {
        int orow = wo * 64 + mt * 16 + u;
        int jc = ks * 4 + quad;
        bf16x8 afrag = load8(&Wtile[buf][orow * KSLOT + ((jc ^ (orow & 7)) << 3)]);
#pragma unroll
        for (int nt = 0; nt < 2; ++nt)
          acc[mt][nt] =
              __builtin_amdgcn_mfma_f32_16x16x32_bf16(afrag, bfrag[nt], acc[mt][nt], 0, 0, 0);
      }
    }
    __syncthreads();  // single barrier: drains W[c+1] async, publishes Pt[nbuf]
  }

  // ---- epilogue: D row = o (quad*4+r), col = x (lane&15) ----
#pragma unroll
  for (int mt = 0; mt < 4; ++mt)
#pragma unroll
    for (int nt = 0; nt < 2; ++nt)
#pragma unroll
      for (int r = 0; r < 4; ++r) {
        int o = wo * 64 + mt * 16 + quad * 4 + r;
        int x = wx * 32 + nt * 16 + u;
        out[((b * OO + o) * HH + y) * WW + x] = acc[mt][nt][r] + bias_s[o];
      }
}

extern "C" void kernel_launch(void* const* d_in, const int* in_sizes, int n_in,
                              void* d_out, int out_size, void* d_ws, size_t ws_size,
                              hipStream_t stream) {
  const float* image = (const float*)d_in[0];
  const float* wl = (const float*)d_in[1];
  const float* wv = (const float*)d_in[2];
  const float* bias = (const float*)d_in[3];
  float* out = (float*)d_out;
  unsigned short* Wt = (unsigned short*)d_ws;  // 64*128*64 bf16 = 1 MB

  int prep_elems = CC * OO * KSLOT;
  prep_kernel<<<(prep_elems + 255) / 256, 256, 0, stream>>>(wl, wv, Wt);
  qconv_kernel<<<BB * HH, 256, 0, stream>>>(image, Wt, bias, out);
}

// Round 3
// 104.282 us; speedup vs baseline: 1.3983x; 1.3983x over previous
//
#include <hip/hip_runtime.h>
#include <stdint.h>

typedef __bf16 bf16x8 __attribute__((ext_vector_type(8)));
typedef __bf16 bf16x2 __attribute__((ext_vector_type(2)));
typedef float f32x16 __attribute__((ext_vector_type(16)));

#define CC 64
#define HH 64
#define WW 64
#define OO 128
#define BB 4

// Product table t=0..24: 20 orbit reps (i+j<8) + 5 reflection-fixed (i+j=8).
// half h computes q[TI]*q[TJ] with q[k] = h ? p[8-k] : p[k]:
//   h=0 covers pairs with i+j<8 plus the 5 fixed; h=1 covers i+j>8 (+dups of fixed, weight 0)
__device__ constexpr int TI[25] = {0,0,0,0,0,0,0,0, 1,1,1,1,1,1, 2,2,2,2, 3,3, 0,1,2,3,4};
__device__ constexpr int TJ[25] = {0,1,2,3,4,5,6,7, 1,2,3,4,5,6, 2,3,4,5, 3,4, 8,7,6,5,4};

// pack two f32 -> one uint32 of two bf16. Prep and the main kernel use the SAME
// function, so the lo/hi convention cancels between A and B fragments.
__device__ __forceinline__ unsigned int pack_bf16(float a, float b) {
#if __has_builtin(__builtin_amdgcn_cvt_pk_bf16_f32)
  bf16x2 r = __builtin_amdgcn_cvt_pk_bf16_f32(a, b);
  return __builtin_bit_cast(unsigned int, r);
#else
  unsigned int ua = __float_as_uint(a) + 0x8000u;  // round-half-up
  unsigned int ub = __float_as_uint(b) + 0x8000u;
  return (ua >> 16) | (ub & 0xFFFF0000u);
#endif
}

// weight value for (n, c, half h, recipe index u in 0..31)
__device__ float wval(const float* __restrict__ wl, const float* __restrict__ wv,
                      int n, int c, int h, int u) {
  if (u < 7) {
    if (h == 0) return wl[(n * CC + c) * 9 + u];
    int k = 8 - u;                       // u=0 -> wl[8], u=1 -> wl[7], else dup (weight 0)
    return (u < 2) ? wl[(n * CC + c) * 9 + k] : 0.f;
  }
  int tt = u - 7;
  int a = TI[tt], bq = TJ[tt];
  if (h == 0) return wv[((n * CC + c) * 9 + a) * 9 + bq];
  if (tt >= 20) return 0.f;              // reflection-fixed: h0 owns the weight
  int a2 = 8 - bq, b2 = 8 - a;           // reflected pair (a2<=b2, i+j>8)
  return wv[((n * CC + c) * 9 + a2) * 9 + b2];
}

// ---- prep: Wt as uint32[(((c*4+ot)*4+ks)*64 + lane)*4 + epair] ----
// A-frag for wave (ot): o = ot*32 + (lane&31), h = lane>>5, k-in-frag = epair*2 {+0,+1}
__global__ void prep_kernel(const float* __restrict__ wl, const float* __restrict__ wv,
                            unsigned int* __restrict__ Wt) {
  int t = blockIdx.x * 256 + threadIdx.x;     // one thread per uint32, coalesced store
  if (t >= CC * 4 * 4 * 64 * 4) return;
  int ep = t & 3;
  int lane = (t >> 2) & 63;
  int ks = (t >> 8) & 3;
  int ot = (t >> 10) & 3;
  int c = t >> 12;
  int n = ot * 32 + (lane & 31);
  int h = lane >> 5;
  int u0 = ks * 8 + ep * 2;
  float v0 = wval(wl, wv, n, c, h, u0);
  float v1 = wval(wl, wv, n, c, h, u0 + 1);
  Wt[t] = pack_bf16(v0, v1);
}

// ---- main kernel: no LDS / no barriers in the c-loop ----
// grid 256 = (b,y); block 1024 = 16 waves = (ot 0..3) x (wx 0..1) x (ch 0..1)
__global__ __launch_bounds__(1024, 4) void qconv_kernel(
    const float* __restrict__ img, const unsigned int* __restrict__ Wt,
    const float* __restrict__ bias, float* __restrict__ out) {
  __shared__ float red[8][64][16];   // 32 KB, used once in epilogue

  const int t = threadIdx.x;
  const int lane = t & 63;
  const int wq = t >> 6;
  const int ot = wq & 3;
  const int wx = (wq >> 2) & 1;
  const int ch = wq >> 3;
  const int n5 = lane & 31;
  const int h = lane >> 5;
  const int b = blockIdx.x >> 6;
  const int y = blockIdx.x & 63;
  const int x = wx * 32 + n5;

  f32x16 acc;
#pragma unroll
  for (int i = 0; i < 16; ++i) acc[i] = 0.f;

  const int c0 = ch * 32;
  for (int c = c0; c < c0 + 32; ++c) {
    // --- per-lane 3x3 patch, zero-padded ---
    float p[9];
    const float* plane = img + ((b * CC + c) * HH) * WW;
#pragma unroll
    for (int r = 0; r < 3; ++r) {
      int yy = y + r - 1;
      bool okY = (unsigned)yy < 64u;
      const float* rowp = plane + yy * WW;
#pragma unroll
      for (int dx = 0; dx < 3; ++dx) {
        int xx = x + dx - 1;
        float v = 0.f;
        if (okY && (unsigned)xx < 64u) v = rowp[xx];
        p[r * 3 + dx] = v;
      }
    }
    // --- reflected view for upper lane-half: identical code both halves ---
    float q[9];
#pragma unroll
    for (int k = 0; k < 9; ++k) q[k] = h ? p[8 - k] : p[k];
    // --- 32 slot values: 7 linear + 25 products ---
    float vals[32];
#pragma unroll
    for (int u = 0; u < 7; ++u) vals[u] = q[u];
#pragma unroll
    for (int tt = 0; tt < 25; ++tt) vals[7 + tt] = q[TI[tt]] * q[TJ[tt]];
    // --- pack to bf16 pairs (same convention as prep) ---
    unsigned int pk[16];
#pragma unroll
    for (int i = 0; i < 16; ++i) pk[i] = pack_bf16(vals[2 * i], vals[2 * i + 1]);

    // --- 4 k-steps: A direct from global (frag-ordered, L1/L2-hot), B from regs ---
    const unsigned int* wbase = Wt + ((c * 4 + ot) * 4) * 256 + lane * 4;
#pragma unroll
    for (int ks = 0; ks < 4; ++ks) {
      uint4 araw = *(const uint4*)(wbase + ks * 256);
      bf16x8 afrag = __builtin_bit_cast(bf16x8, araw);
      uint4 braw = make_uint4(pk[ks * 4], pk[ks * 4 + 1], pk[ks * 4 + 2], pk[ks * 4 + 3]);
      bf16x8 bfrag = __builtin_bit_cast(bf16x8, braw);
      acc = __builtin_amdgcn_mfma_f32_32x32x16_bf16(afrag, bfrag, acc, 0, 0, 0);
    }
  }

  // --- combine the two c-halves (only cross-wave exchange in the kernel) ---
  float* redp = &red[ot * 2 + wx][lane][0];
  if (ch == 1) {
#pragma unroll
    for (int r = 0; r < 16; ++r) redp[r] = acc[r];
  }
  __syncthreads();
  if (ch == 0) {
#pragma unroll
    for (int r = 0; r < 16; ++r) {
      int row = (r & 3) + 8 * (r >> 2) + 4 * h;   // 32x32 C/D layout (m74/m101)
      int o = ot * 32 + row;
      out[((b * OO + o) * HH + y) * WW + x] = acc[r] + redp[r] + bias[o];
    }
  }
}

extern "C" void kernel_launch(void* const* d_in, const int* in_sizes, int n_in,
                              void* d_out, int out_size, void* d_ws, size_t ws_size,
                              hipStream_t stream) {
  const float* image = (const float*)d_in[0];
  const float* wl = (const float*)d_in[1];
  const float* wv = (const float*)d_in[2];
  const float* bias = (const float*)d_in[3];
  float* out = (float*)d_out;
  unsigned int* Wt = (unsigned int*)d_ws;  // 262144 uints = 1 MB

  int prep_elems = CC * 4 * 4 * 64 * 4;    // 262144
  prep_kernel<<<(prep_elems + 255) / 256, 256, 0, stream>>>(wl, wv, Wt);
  qconv_kernel<<<BB * HH, 1024, 0, stream>>>(image, Wt, bias, out);
}